// Round 1
// 439.783 us; speedup vs baseline: 1.2306x; 1.2306x over previous
//
#include <hip/hip_runtime.h>

// Flash cross-attention, B=32, Tq=512, Tk=2048, D=512, fp32 in/out.
// Round 4 restructure:
//  - Precision split moved Q-side: QK^T = (Qhi+Qlo) x K_rne  -> KloL gone.
//  - Redundant per-wave in-register softmax (all 64 lanes), no Pl/alpha LDS.
//  - PV computed transposed (O^T = V^T P^T): P-frag & alpha are lane-local.
//  - 2 barriers/tile pipeline: loads(t+1)+Vt-write(t)+QK(t) | softmax+PV(t)+Kf-write(t+1).
//  - Sp padded to 20 floats/row (softmax-read bank conflicts), setprio on MFMA.

#define BATCH 32
#define TQ 512
#define TK 2048
#define DIM 512
#define MQ 32
#define NK 16
#define NKT (TK / NK)   // 128 k-tiles

typedef __attribute__((ext_vector_type(8))) _Float16 half8;
typedef __attribute__((ext_vector_type(2))) _Float16 half2v;
typedef __attribute__((ext_vector_type(4))) float float4v;
typedef __attribute__((ext_vector_type(4))) int int4v;

__device__ __forceinline__ half2v pkrtz(float a, float b) {
  auto r = __builtin_amdgcn_cvt_pkrtz(a, b);  // __fp16 x2
  half2v o;
  o[0] = (_Float16)r[0];
  o[1] = (_Float16)r[1];
  return o;
}

__global__ __launch_bounds__(256, 2)
void attn_flash3(const float* __restrict__ dec, const float* __restrict__ enc,
                 float* __restrict__ out) {
  const int id = blockIdx.x;
  const int b = ((id & 7) << 2) + ((id >> 3) & 3);  // XCD-clustered batches
  const int q0 = (id >> 5) * MQ;
  const int tid = threadIdx.x;
  const int wave = tid >> 6;
  const int lane = tid & 63;
  const int quad = lane >> 4;
  const int l16 = lane & 15;

  // K tile fragment-major (RNE f16): chunk sg (d=32sg..+32), slot quad*16+key
  // holds K[key][32sg+8*quad .. +8].
  __shared__ __align__(16) _Float16 KfL[16 * 64 * 8];   // 16 KB
  __shared__ __align__(16) _Float16 VtL[DIM * NK];      // 16 KB, Vt[d][k]
  __shared__ __align__(16) float Sp[4][MQ][20];         // 10 KB (padded rows)

  // ---- Q fragments: hi/lo split over this wave's d-quarter ----
  half8 qhi[2][4], qlo[2][4];
#pragma unroll
  for (int mt = 0; mt < 2; ++mt) {
    const float* qrow =
        dec + ((size_t)b * TQ + (q0 + mt * 16 + l16)) * DIM + wave * 128 + quad * 8;
#pragma unroll
    for (int s = 0; s < 4; ++s) {
      float4v v0 = *(const float4v*)(qrow + s * 32);
      float4v v1 = *(const float4v*)(qrow + s * 32 + 4);
#pragma unroll
      for (int j = 0; j < 4; ++j) {
        float f0 = v0[j], f1 = v1[j];
        _Float16 h0 = (_Float16)f0;   // RNE
        _Float16 h1 = (_Float16)f1;
        qhi[mt][s][j] = h0;
        qhi[mt][s][j + 4] = h1;
        qlo[mt][s][j] = (_Float16)(f0 - (float)h0);
        qlo[mt][s][j + 4] = (_Float16)(f1 - (float)h1);
      }
    }
  }

  float4v acc[2][8];
#pragma unroll
  for (int mt = 0; mt < 2; ++mt)
#pragma unroll
    for (int t = 0; t < 8; ++t) acc[mt][t] = float4v{0.f, 0.f, 0.f, 0.f};

  // per-lane online-softmax state for row R = (quad>>1)*16 + l16
  float m_r = -INFINITY, l_r = 0.0f;

  const float* encb = enc + (size_t)b * TK * DIM;
  const int key = tid & 15;
  const int drow = tid >> 4;  // dbase = drow*8 + i*128
  const int sgb = drow >> 2;           // chunk base
  const int slot = ((drow & 3) << 4) + key;

  float4v pf[8];
  half8 nxt[4];

  // ---- prologue: tile 0 -> regs -> convert -> KfL + nxt ----
  {
    const float* kp = encb + (size_t)key * DIM + drow * 8;
#pragma unroll
    for (int i = 0; i < 4; ++i) {
      pf[2 * i] = *(const float4v*)(kp + i * 128);
      pf[2 * i + 1] = *(const float4v*)(kp + i * 128 + 4);
    }
#pragma unroll
    for (int i = 0; i < 4; ++i) {
      half8 h;
#pragma unroll
      for (int j = 0; j < 4; ++j) {
        h[j] = (_Float16)pf[2 * i][j];          // RNE
        h[j + 4] = (_Float16)pf[2 * i + 1][j];
      }
      *(half8*)&KfL[((sgb + i * 4) * 64 + slot) * 8] = h;
      nxt[i] = h;
    }
  }
  __syncthreads();

  for (int kt = 0; kt < NKT; ++kt) {
    // ================= phase 1 =================
    // issue global loads for tile kt+1 (wraps; harmless re-read)
    {
      const int k0n = ((kt + 1) & (NKT - 1)) * NK;
      const float* kp = encb + (size_t)(k0n + key) * DIM + drow * 8;
#pragma unroll
      for (int i = 0; i < 4; ++i) {
        pf[2 * i] = *(const float4v*)(kp + i * 128);
        pf[2 * i + 1] = *(const float4v*)(kp + i * 128 + 4);
      }
    }
    // Vt write for tile kt (from regs staged last iter)
#pragma unroll
    for (int i = 0; i < 4; ++i) {
      const int dbase = drow * 8 + i * 128;
#pragma unroll
      for (int j = 0; j < 8; ++j) VtL[(dbase + j) * NK + key] = nxt[i][j];
    }
    // QK^T over this wave's d-quarter: (Qhi + Qlo) x K
    {
      float4v s0 = float4v{0.f, 0.f, 0.f, 0.f};
      float4v s1 = float4v{0.f, 0.f, 0.f, 0.f};
      __builtin_amdgcn_s_setprio(1);
#pragma unroll
      for (int s = 0; s < 4; ++s) {
        half8 kf = *(const half8*)&KfL[(((wave << 2) + s) * 64 + lane) * 8];
        s0 = __builtin_amdgcn_mfma_f32_16x16x32_f16(qhi[0][s], kf, s0, 0, 0, 0);
        s0 = __builtin_amdgcn_mfma_f32_16x16x32_f16(qlo[0][s], kf, s0, 0, 0, 0);
        s1 = __builtin_amdgcn_mfma_f32_16x16x32_f16(qhi[1][s], kf, s1, 0, 0, 0);
        s1 = __builtin_amdgcn_mfma_f32_16x16x32_f16(qlo[1][s], kf, s1, 0, 0, 0);
      }
      __builtin_amdgcn_s_setprio(0);
#pragma unroll
      for (int r = 0; r < 4; ++r) {
        Sp[wave][(quad << 2) + r][l16] = s0[r];
        Sp[wave][16 + (quad << 2) + r][l16] = s1[r];
      }
    }
    __syncthreads();

    // ================= phase 2 =================
    // in-register softmax, redundant per wave. Lane owns row R, keys kb..kb+8.
    half8 pB0, pB1;
    float al0, al1;
    {
      const int R = ((quad >> 1) << 4) + l16;
      const int kb = (quad & 1) << 3;
      float4v sa = float4v{0.f, 0.f, 0.f, 0.f};
      float4v sb = float4v{0.f, 0.f, 0.f, 0.f};
#pragma unroll
      for (int w = 0; w < 4; ++w) {
        sa += *(const float4v*)&Sp[w][R][kb];
        sb += *(const float4v*)&Sp[w][R][kb + 4];
      }
      float mx = fmaxf(fmaxf(fmaxf(sa[0], sa[1]), fmaxf(sa[2], sa[3])),
                       fmaxf(fmaxf(sb[0], sb[1]), fmaxf(sb[2], sb[3])));
      mx = fmaxf(mx, __shfl_xor(mx, 16));          // full row max (16 keys)
      const float mnew = fmaxf(m_r, mx);
      const float al = __expf(m_r - mnew);
      float p[8];
      float sum = 0.0f;
#pragma unroll
      for (int c = 0; c < 4; ++c) { p[c] = __expf(sa[c] - mnew); sum += p[c]; }
#pragma unroll
      for (int c = 0; c < 4; ++c) { p[4 + c] = __expf(sb[c] - mnew); sum += p[4 + c]; }
      sum += __shfl_xor(sum, 16);                  // full row sum
      m_r = mnew;
      l_r = l_r * al + sum;
      half8 pown;
#pragma unroll
      for (int pr = 0; pr < 4; ++pr) {
        half2v h = pkrtz(p[2 * pr], p[2 * pr + 1]);
        pown[2 * pr] = h[0];
        pown[2 * pr + 1] = h[1];
      }
      // B-frags for PV^T: mt0 rows 0..15 (own), mt1 rows 16..31 (lane^32)
      int4v pi = __builtin_bit_cast(int4v, pown);
      int4v ps;
#pragma unroll
      for (int j = 0; j < 4; ++j) ps[j] = __shfl_xor(pi[j], 32);
      half8 psw = __builtin_bit_cast(half8, ps);
      half8 hz;
#pragma unroll
      for (int j = 0; j < 8; ++j) hz[j] = (_Float16)0.0f;
      pB0 = (quad < 2) ? pown : hz;
      pB1 = (quad < 2) ? psw : hz;
      const float alsw = __shfl_xor(al, 32);
      al0 = (quad < 2) ? al : alsw;
      al1 = (quad < 2) ? alsw : al;
    }

    // PV^T: acc[mt] = V^T x P^T (A = V^T from VtL, B = P from regs)
    {
      half8 hz;
#pragma unroll
      for (int j = 0; j < 8; ++j) hz[j] = (_Float16)0.0f;
      __builtin_amdgcn_s_setprio(1);
#pragma unroll
      for (int t = 0; t < 8; ++t) {
        const int dd = wave * 128 + t * 16 + l16;
        half8 vf = hz;
        if (quad < 2) vf = *(const half8*)&VtL[dd * NK + quad * 8];
        acc[0][t] = acc[0][t] * al0;
        acc[0][t] = __builtin_amdgcn_mfma_f32_16x16x32_f16(vf, pB0, acc[0][t], 0, 0, 0);
        acc[1][t] = acc[1][t] * al1;
        acc[1][t] = __builtin_amdgcn_mfma_f32_16x16x32_f16(vf, pB1, acc[1][t], 0, 0, 0);
      }
      __builtin_amdgcn_s_setprio(0);
    }

    // convert tile kt+1 and write KfL (QK(kt) readers are past barrier 1)
#pragma unroll
    for (int i = 0; i < 4; ++i) {
      half8 h;
#pragma unroll
      for (int j = 0; j < 4; ++j) {
        h[j] = (_Float16)pf[2 * i][j];          // RNE
        h[j + 4] = (_Float16)pf[2 * i + 1][j];
      }
      *(half8*)&KfL[((sgb + i * 4) * 64 + slot) * 8] = h;
      nxt[i] = h;
    }
    __syncthreads();
  }

  // ---- epilogue: O = O^T normalized; contiguous float4 stores ----
  const float lsw = __shfl_xor(l_r, 32);
  const float l0 = (quad < 2) ? l_r : lsw;   // l for row l16
  const float l1 = (quad < 2) ? lsw : l_r;   // l for row 16+l16
  const float linv0 = 1.0f / l0;
  const float linv1 = 1.0f / l1;
#pragma unroll
  for (int mt = 0; mt < 2; ++mt) {
    const float linv = mt ? linv1 : linv0;
    float* orow =
        out + ((size_t)b * TQ + (q0 + mt * 16 + l16)) * DIM + wave * 128 + quad * 4;
#pragma unroll
    for (int t = 0; t < 8; ++t) {
      float4v o = acc[mt][t] * linv;
      *(float4v*)(orow + t * 16) = o;
    }
  }
}

extern "C" void kernel_launch(void* const* d_in, const int* in_sizes, int n_in,
                              void* d_out, int out_size, void* d_ws, size_t ws_size,
                              hipStream_t stream) {
  const float* dec = (const float*)d_in[0];
  const float* enc = (const float*)d_in[1];
  float* out = (float*)d_out;
  attn_flash3<<<dim3(BATCH * (TQ / MQ)), 256, 0, stream>>>(dec, enc, out);
}